// Round 9
// baseline (109.937 us; speedup 1.0000x reference)
//
#include <hip/hip_runtime.h>
#include <hip/hip_bf16.h>

#define BATCH 8192
#define DIM   512
#define NCL   1024
#define ROWS  32
#define BK    32
#define NCH   (DIM / BK)   // 16 chunks of 32 along D
#define NWAVE 16           // 1024 threads

typedef __bf16 bf16x8 __attribute__((ext_vector_type(8)));
typedef float  f32x4  __attribute__((ext_vector_type(4)));

__device__ __forceinline__ unsigned short f2bf(float f) {
  union { float f; unsigned u; } v; v.f = f;
  unsigned r = v.u + 0x7fffu + ((v.u >> 16) & 1u);   // RNE, inputs finite
  return (unsigned short)(r >> 16);
}
__device__ __forceinline__ unsigned pk(float a, float b) {
  return (unsigned)f2bf(a) | ((unsigned)f2bf(b) << 16);
}

// weight [1024][512] fp32 -> chunk-major bf16 wck[16][1024][32], plus wsq[1024].
__global__ __launch_bounds__(256) void prep_w(const float* __restrict__ w,
                                              __hip_bfloat16* __restrict__ wck,
                                              float* __restrict__ wsq) {
  int k    = blockIdx.x * 4 + (threadIdx.x >> 6);
  int lane = threadIdx.x & 63;
  const float4* wrow = (const float4*)(w + (size_t)k * DIM);
  float4 a = wrow[lane * 2 + 0];
  float4 b = wrow[lane * 2 + 1];
  float s = a.x*a.x + a.y*a.y + a.z*a.z + a.w*a.w
          + b.x*b.x + b.y*b.y + b.z*b.z + b.w*b.w;
  #pragma unroll
  for (int m = 32; m >= 1; m >>= 1) s += __shfl_xor(s, m, 64);
  if (lane == 0) wsq[k] = s;
  int c = lane >> 2;
  int j = (lane & 3) * 8;
  uint4 p = { pk(a.x, a.y), pk(a.z, a.w), pk(b.x, b.y), pk(b.z, b.w) };
  *(uint4*)(wck + ((size_t)c * NCL + k) * BK + j) = p;
}

// Fused: 32 rows x 1024 cols per block, 1024 threads = 16 waves, 4 waves/SIMD.
// PAIRED B-READS: waves w and w+8 cover the SAME 128-col strip (rows 0-15 vs
// 16-31) and walk chunks in the SAME order, issuing IDENTICAL B addresses at
// ~the same time -> L1/MSHR merges the duplicate line requests, halving the
// L2 request stream (R8 analysis: fused is bound by L2-service queueing from
// 32 CUs/XCD re-reading the same 1 MB, not by wire bandwidth).
__global__ __launch_bounds__(1024, 4) void fused(const float* __restrict__ x,
                                                 const __hip_bfloat16* __restrict__ wck,
                                                 const float* __restrict__ wsq,
                                                 float* __restrict__ out) {
  __shared__ __align__(16) __hip_bfloat16 xs2[NCH * 2 * 512];   // 32 KB, A-frag layout
  __shared__ float wsq_s[NCL];                                  // 4 KB
  __shared__ float xsq_s[ROWS];
  __shared__ float rowsum[ROWS];

  const int tid = threadIdx.x;
  const int r0  = blockIdx.x * ROWS;

  const int wave = tid >> 6;
  const int lane = tid & 63;
  const int m16  = lane & 15;
  const int quad = lane >> 4;
  const int rt   = wave >> 3;          // row-tile: waves 0-7 -> rows 0-15, 8-15 -> 16-31
  const int col0 = (wave & 7) * 128;   // 128-col strip shared by the pair (w, w+8)

  // ---- prologue: chunk-0 B loads (pair-mates issue identical addresses) ----
  bf16x8 bcur[8];
  {
    const __hip_bfloat16* wp0 = wck + (size_t)(col0 + m16) * BK + quad * 8;
    #pragma unroll
    for (int ct = 0; ct < 8; ++ct)
      bcur[ct] = *(const bf16x8*)(wp0 + ct * (16 * BK));
  }

  // ---- stage x fp32->bf16 into A-frag layout + per-row sumsq (half-wave/row) ----
  {
    int row = tid >> 5;                // 0..31: one 32-lane half-wave per row
    int seg = tid & 31;                // 16 consecutive d each
    int c = seg >> 1, h = seg & 1;     // chunk, half-of-chunk
    int rw = row >> 4, m = row & 15;
    const f32x4* src = (const f32x4*)(x + (size_t)(r0 + row) * DIM + seg * 16);
    f32x4 v0 = src[0], v1 = src[1], v2 = src[2], v3 = src[3];
    float ss = v0.x*v0.x + v0.y*v0.y + v0.z*v0.z + v0.w*v0.w
             + v1.x*v1.x + v1.y*v1.y + v1.z*v1.z + v1.w*v1.w
             + v2.x*v2.x + v2.y*v2.y + v2.z*v2.z + v2.w*v2.w
             + v3.x*v3.x + v3.y*v3.y + v3.z*v3.z + v3.w*v3.w;
    __hip_bfloat16* base = xs2 + (c * 2 + rw) * 512 + m * 8;
    uint4 p0 = { pk(v0.x, v0.y), pk(v0.z, v0.w), pk(v1.x, v1.y), pk(v1.z, v1.w) };
    uint4 p1 = { pk(v2.x, v2.y), pk(v2.z, v2.w), pk(v3.x, v3.y), pk(v3.z, v3.w) };
    *(uint4*)(base + (h * 2 + 0) * 128) = p0;   // quad h*2
    *(uint4*)(base + (h * 2 + 1) * 128) = p1;   // quad h*2+1
    ss += __shfl_xor(ss, 1, 64);
    ss += __shfl_xor(ss, 2, 64);
    ss += __shfl_xor(ss, 4, 64);
    ss += __shfl_xor(ss, 8, 64);
    ss += __shfl_xor(ss, 16, 64);      // reduce within the 32-lane half
    if ((lane & 31) == 0) xsq_s[row] = ss;
    wsq_s[tid] = wsq[tid];
    if (tid < ROWS) rowsum[tid] = 0.f; // for epilogue LDS atomics
  }

  f32x4 acc[8];
  #pragma unroll
  for (int ct = 0; ct < 8; ++ct)
    acc[ct] = (f32x4){0.f, 0.f, 0.f, 0.f};

  __syncthreads();                     // the ONLY barrier before the epilogue

  bf16x8 a_cur = *(const bf16x8*)(xs2 + (0 * 2 + rt) * 512 + lane * 8);

  // ---- K-loop: chunk order 0..15 (pair-sync for L1 dedup), dist-1 prefetch ----
  #pragma unroll
  for (int c = 0; c < NCH; ++c) {
    bf16x8 bnx[8], a_nxt;
    if (c + 1 < NCH) {
      const __hip_bfloat16* wp = wck + ((size_t)(c + 1) * NCL + col0 + m16) * BK + quad * 8;
      #pragma unroll
      for (int ct = 0; ct < 8; ++ct)
        bnx[ct] = *(const bf16x8*)(wp + ct * (16 * BK));
      a_nxt = *(const bf16x8*)(xs2 + ((c + 1) * 2 + rt) * 512 + lane * 8);
    }
    #pragma unroll
    for (int ct = 0; ct < 8; ++ct)
      acc[ct] = __builtin_amdgcn_mfma_f32_16x16x32_bf16(a_cur, bcur[ct], acc[ct], 0, 0, 0);
    if (c + 1 < NCH) {
      a_cur = a_nxt;
      #pragma unroll
      for (int ct = 0; ct < 8; ++ct) bcur[ct] = bnx[ct];
    }
  }

  // ---- epilogue: dist -> q_unnorm, LDS-atomic row sums, normalize ----
  // C/D layout: col = lane&15, row = quad*4 + reg (verified m89/m91)
  float part[4] = {0.f, 0.f, 0.f, 0.f};
  float xq[4];
  #pragma unroll
  for (int i = 0; i < 4; ++i) xq[i] = xsq_s[rt * 16 + quad * 4 + i];
  #pragma unroll
  for (int ct = 0; ct < 8; ++ct) {
    float wq = wsq_s[col0 + ct * 16 + m16];
    #pragma unroll
    for (int i = 0; i < 4; ++i) {
      float dist = fmaxf(xq[i] + wq - 2.f * acc[ct][i], 0.f);
      float qu = 1.f / (1.f + dist);    // ALPHA=1: (1+dist)^-1 exact
      acc[ct][i] = qu;
      part[i] += qu;
    }
  }
  #pragma unroll
  for (int i = 0; i < 4; ++i) {
    float s = part[i];
    s += __shfl_xor(s, 1, 64);
    s += __shfl_xor(s, 2, 64);
    s += __shfl_xor(s, 4, 64);
    s += __shfl_xor(s, 8, 64);
    part[i] = s;
  }
  if (m16 == 0) {
    #pragma unroll
    for (int i = 0; i < 4; ++i)
      atomicAdd(&rowsum[rt * 16 + quad * 4 + i], part[i]);
  }
  __syncthreads();
  #pragma unroll
  for (int i = 0; i < 4; ++i) {
    int r = rt * 16 + quad * 4 + i;
    float inv = 1.f / rowsum[r];
    float* orow = out + (size_t)(r0 + r) * NCL + col0 + m16;
    #pragma unroll
    for (int ct = 0; ct < 8; ++ct)
      orow[ct * 16] = acc[ct][i] * inv;
  }
}

extern "C" void kernel_launch(void* const* d_in, const int* in_sizes, int n_in,
                              void* d_out, int out_size, void* d_ws, size_t ws_size,
                              hipStream_t stream) {
  const float* x = (const float*)d_in[0];   // [8192][512] fp32
  const float* w = (const float*)d_in[1];   // [1024][512] fp32
  __hip_bfloat16* wck = (__hip_bfloat16*)d_ws;                      // 1 MB
  float* wsq = (float*)((char*)d_ws + (size_t)NCH * NCL * BK * 2);  // +4 KB
  float* out = (float*)d_out;

  hipLaunchKernelGGL(prep_w, dim3(NCL / 4), dim3(256), 0, stream, w, wck, wsq);
  hipLaunchKernelGGL(fused, dim3(BATCH / ROWS), dim3(1024), 0, stream, x, wck, wsq, out);
}

// Round 10
// 95.428 us; speedup vs baseline: 1.1520x; 1.1520x over previous
//
#include <hip/hip_runtime.h>
#include <hip/hip_bf16.h>

#define BATCH 8192
#define DIM   512
#define NCL   1024
#define ROWS  32
#define BK    32
#define NCH   (DIM / BK)   // 16 chunks of 32 along D
#define NWAVE 16           // 1024 threads

typedef __bf16 bf16x8 __attribute__((ext_vector_type(8)));
typedef float  f32x4  __attribute__((ext_vector_type(4)));

__device__ __forceinline__ unsigned short f2bf(float f) {
  union { float f; unsigned u; } v; v.f = f;
  unsigned r = v.u + 0x7fffu + ((v.u >> 16) & 1u);   // RNE, inputs finite
  return (unsigned short)(r >> 16);
}
__device__ __forceinline__ unsigned pk(float a, float b) {
  return (unsigned)f2bf(a) | ((unsigned)f2bf(b) << 16);
}

// weight [1024][512] fp32 -> chunk-major bf16 wck[16][1024][32], plus wsq[1024].
__global__ __launch_bounds__(256) void prep_w(const float* __restrict__ w,
                                              __hip_bfloat16* __restrict__ wck,
                                              float* __restrict__ wsq) {
  int k    = blockIdx.x * 4 + (threadIdx.x >> 6);
  int lane = threadIdx.x & 63;
  const float4* wrow = (const float4*)(w + (size_t)k * DIM);
  float4 a = wrow[lane * 2 + 0];
  float4 b = wrow[lane * 2 + 1];
  float s = a.x*a.x + a.y*a.y + a.z*a.z + a.w*a.w
          + b.x*b.x + b.y*b.y + b.z*b.z + b.w*b.w;
  #pragma unroll
  for (int m = 32; m >= 1; m >>= 1) s += __shfl_xor(s, m, 64);
  if (lane == 0) wsq[k] = s;
  int c = lane >> 2;
  int j = (lane & 3) * 8;
  uint4 p = { pk(a.x, a.y), pk(a.z, a.w), pk(b.x, b.y), pk(b.z, b.w) };
  *(uint4*)(wck + ((size_t)c * NCL + k) * BK + j) = p;
}

// Fused: 32 rows x 1024 cols per block, 16 waves (each: 64-col strip, 2x4 tiles),
// 4 waves/SIMD, wave-staggered chunk order (R8 best). NEW: the B prefetch is
// pinned with sched_barrier(0) per chunk — R9's profile showed VGPR_Count=40,
// proving the compiler was sinking all prefetch loads to their uses and
// serializing the K-loop on L2 latency. Distance-2 B pipeline, distance-1 A.
__global__ __launch_bounds__(1024, 4) void fused(const float* __restrict__ x,
                                                 const __hip_bfloat16* __restrict__ wck,
                                                 const float* __restrict__ wsq,
                                                 float* __restrict__ out) {
  __shared__ __align__(16) __hip_bfloat16 xs2[NCH * 2 * 512];   // 32 KB, A-frag layout
  __shared__ float wsq_s[NCL];                                  // 4 KB
  __shared__ float xsq_s[ROWS];
  __shared__ float rowsum[ROWS];

  const int tid = threadIdx.x;
  const int r0  = blockIdx.x * ROWS;

  const int wave = tid >> 6;
  const int lane = tid & 63;
  const int m16  = lane & 15;
  const int quad = lane >> 4;
  const int col0 = wave * 64;          // 64-col strip per wave
  const int c0   = wave;               // staggered starting chunk (0..15)

  // ---- prologue: B loads for this wave's first TWO chunks, issued pre-staging ----
  bf16x8 b0[4], b1[4];
  {
    const __hip_bfloat16* wp0 = wck + ((size_t)c0 * NCL + col0 + m16) * BK + quad * 8;
    #pragma unroll
    for (int ct = 0; ct < 4; ++ct) b0[ct] = *(const bf16x8*)(wp0 + ct * (16 * BK));
    int c1 = (c0 + 1) & (NCH - 1);
    const __hip_bfloat16* wp1 = wck + ((size_t)c1 * NCL + col0 + m16) * BK + quad * 8;
    #pragma unroll
    for (int ct = 0; ct < 4; ++ct) b1[ct] = *(const bf16x8*)(wp1 + ct * (16 * BK));
  }

  // ---- stage x fp32->bf16 into A-frag layout + per-row sumsq (half-wave/row) ----
  {
    int row = tid >> 5;                // 0..31: one 32-lane half-wave per row
    int seg = tid & 31;                // 16 consecutive d each
    int c = seg >> 1, h = seg & 1;     // chunk, half-of-chunk
    int rw = row >> 4, m = row & 15;
    const f32x4* src = (const f32x4*)(x + (size_t)(r0 + row) * DIM + seg * 16);
    f32x4 v0 = src[0], v1 = src[1], v2 = src[2], v3 = src[3];
    float ss = v0.x*v0.x + v0.y*v0.y + v0.z*v0.z + v0.w*v0.w
             + v1.x*v1.x + v1.y*v1.y + v1.z*v1.z + v1.w*v1.w
             + v2.x*v2.x + v2.y*v2.y + v2.z*v2.z + v2.w*v2.w
             + v3.x*v3.x + v3.y*v3.y + v3.z*v3.z + v3.w*v3.w;
    __hip_bfloat16* base = xs2 + (c * 2 + rw) * 512 + m * 8;
    uint4 p0 = { pk(v0.x, v0.y), pk(v0.z, v0.w), pk(v1.x, v1.y), pk(v1.z, v1.w) };
    uint4 p1 = { pk(v2.x, v2.y), pk(v2.z, v2.w), pk(v3.x, v3.y), pk(v3.z, v3.w) };
    *(uint4*)(base + (h * 2 + 0) * 128) = p0;   // quad h*2
    *(uint4*)(base + (h * 2 + 1) * 128) = p1;   // quad h*2+1
    ss += __shfl_xor(ss, 1, 64);
    ss += __shfl_xor(ss, 2, 64);
    ss += __shfl_xor(ss, 4, 64);
    ss += __shfl_xor(ss, 8, 64);
    ss += __shfl_xor(ss, 16, 64);      // reduce within the 32-lane half
    if ((lane & 31) == 0) xsq_s[row] = ss;
    wsq_s[tid] = wsq[tid];
    if (tid < ROWS) rowsum[tid] = 0.f; // for epilogue LDS atomics
  }

  f32x4 acc[2][4];
  #pragma unroll
  for (int rt = 0; rt < 2; ++rt)
    #pragma unroll
    for (int ct = 0; ct < 4; ++ct)
      acc[rt][ct] = (f32x4){0.f, 0.f, 0.f, 0.f};

  __syncthreads();                     // the ONLY barrier before the epilogue

  bf16x8 a0 = *(const bf16x8*)(xs2 + (c0 * 2 + 0) * 512 + lane * 8);
  bf16x8 a1 = *(const bf16x8*)(xs2 + (c0 * 2 + 1) * 512 + lane * 8);

  // ---- K-loop: staggered chunks; B dist-2 + A dist-1 prefetch, PINNED by
  //      sched_barrier(0) so the compiler cannot sink the loads to their uses ----
  #pragma unroll
  for (int it = 0; it < NCH; ++it) {
    bf16x8 b2[4], a0n, a1n;
    if (it + 2 < NCH) {
      int cp = (c0 + it + 2) & (NCH - 1);
      const __hip_bfloat16* wp = wck + ((size_t)cp * NCL + col0 + m16) * BK + quad * 8;
      #pragma unroll
      for (int ct = 0; ct < 4; ++ct)
        b2[ct] = *(const bf16x8*)(wp + ct * (16 * BK));
    }
    if (it + 1 < NCH) {
      int cn = (c0 + it + 1) & (NCH - 1);
      a0n = *(const bf16x8*)(xs2 + (cn * 2 + 0) * 512 + lane * 8);
      a1n = *(const bf16x8*)(xs2 + (cn * 2 + 1) * 512 + lane * 8);
    }
    __builtin_amdgcn_sched_barrier(0);   // loads above may not sink below
    #pragma unroll
    for (int ct = 0; ct < 4; ++ct) {
      acc[0][ct] = __builtin_amdgcn_mfma_f32_16x16x32_bf16(a0, b0[ct], acc[0][ct], 0, 0, 0);
      acc[1][ct] = __builtin_amdgcn_mfma_f32_16x16x32_bf16(a1, b0[ct], acc[1][ct], 0, 0, 0);
    }
    // rotate pipeline (full unroll -> pure register renaming, no movs)
    #pragma unroll
    for (int ct = 0; ct < 4; ++ct) b0[ct] = b1[ct];
    if (it + 2 < NCH) {
      #pragma unroll
      for (int ct = 0; ct < 4; ++ct) b1[ct] = b2[ct];
    }
    if (it + 1 < NCH) { a0 = a0n; a1 = a1n; }
  }

  // ---- epilogue: dist -> q_unnorm, LDS-atomic row sums, normalize ----
  // C/D layout: col = lane&15, row = quad*4 + reg (verified m89/m91)
  float part[2][4];
  #pragma unroll
  for (int rt = 0; rt < 2; ++rt) {
    float xq[4];
    #pragma unroll
    for (int i = 0; i < 4; ++i) { xq[i] = xsq_s[rt * 16 + quad * 4 + i]; part[rt][i] = 0.f; }
    #pragma unroll
    for (int ct = 0; ct < 4; ++ct) {
      float wq = wsq_s[col0 + ct * 16 + m16];
      #pragma unroll
      for (int i = 0; i < 4; ++i) {
        float dist = fmaxf(xq[i] + wq - 2.f * acc[rt][ct][i], 0.f);
        float qu = 1.f / (1.f + dist);    // ALPHA=1: (1+dist)^-1 exact
        acc[rt][ct][i] = qu;
        part[rt][i] += qu;
      }
    }
  }
  #pragma unroll
  for (int rt = 0; rt < 2; ++rt)
    #pragma unroll
    for (int i = 0; i < 4; ++i) {
      float s = part[rt][i];
      s += __shfl_xor(s, 1, 64);
      s += __shfl_xor(s, 2, 64);
      s += __shfl_xor(s, 4, 64);
      s += __shfl_xor(s, 8, 64);
      part[rt][i] = s;
    }
  if (m16 == 0) {
    #pragma unroll
    for (int rt = 0; rt < 2; ++rt)
      #pragma unroll
      for (int i = 0; i < 4; ++i)
        atomicAdd(&rowsum[rt * 16 + quad * 4 + i], part[rt][i]);
  }
  __syncthreads();
  #pragma unroll
  for (int rt = 0; rt < 2; ++rt) {
    #pragma unroll
    for (int i = 0; i < 4; ++i) {
      int r = rt * 16 + quad * 4 + i;
      float inv = 1.f / rowsum[r];
      float* orow = out + (size_t)(r0 + r) * NCL + col0 + m16;
      #pragma unroll
      for (int ct = 0; ct < 4; ++ct)
        orow[ct * 16] = acc[rt][ct][i] * inv;
    }
  }
}

extern "C" void kernel_launch(void* const* d_in, const int* in_sizes, int n_in,
                              void* d_out, int out_size, void* d_ws, size_t ws_size,
                              hipStream_t stream) {
  const float* x = (const float*)d_in[0];   // [8192][512] fp32
  const float* w = (const float*)d_in[1];   // [1024][512] fp32
  __hip_bfloat16* wck = (__hip_bfloat16*)d_ws;                      // 1 MB
  float* wsq = (float*)((char*)d_ws + (size_t)NCH * NCL * BK * 2);  // +4 KB
  float* out = (float*)d_out;

  hipLaunchKernelGGL(prep_w, dim3(NCL / 4), dim3(256), 0, stream, w, wck, wsq);
  hipLaunchKernelGGL(fused, dim3(BATCH / ROWS), dim3(1024), 0, stream, x, wck, wsq, out);
}